// Round 4
// baseline (194.553 us; speedup 1.0000x reference)
//
#include <hip/hip_runtime.h>
#include <hip/hip_bf16.h>

// B=8, Ct=256, Cs=128, H=W=32, S=1024, E=256, nH=8, hd=32
typedef unsigned short u16;
typedef __attribute__((ext_vector_type(8))) short short8;
typedef __attribute__((ext_vector_type(4))) float f32x4;
typedef __attribute__((ext_vector_type(4))) unsigned short u16x4;

static __device__ __forceinline__ u16 f2bf(float x) {
  __hip_bfloat16 b = __float2bfloat16(x);
  return *reinterpret_cast<u16*>(&b);
}
// truncating f32->bf16 (1 instr); ~0.2% low bias, fine for P (attn-internal)
static __device__ __forceinline__ u16 f2bf_trunc(float x) {
  union { float f; unsigned u; } v;
  v.f = x;
  return (u16)(v.u >> 16);
}

#define QSCALE 0.17677669529663687f

// ---------------------------------------------------------------------------
// Prep: WqB = Wq*qscale (256x256 bf16), WkvB = [Wk@kv_w; Wv@kv_w] (512x128 bf16)
//       M2B = fuse_w@out_proj_w (256x256 bf16), qbias, bnpk {inv, off}
// ---------------------------------------------------------------------------
__global__ __launch_bounds__(256) void prep_kernel(
    const float* __restrict__ in_proj_w, const float* __restrict__ in_proj_b,
    const float* __restrict__ kv_w, const float* __restrict__ fuse_w,
    const float* __restrict__ out_proj_w, const float* __restrict__ out_proj_b,
    const float* __restrict__ gamma, const float* __restrict__ beta,
    const float* __restrict__ mean, const float* __restrict__ var,
    u16* __restrict__ WqB, u16* __restrict__ WkvB, u16* __restrict__ M2B,
    float* __restrict__ qbias, float2* __restrict__ bnpk) {
  int idx = blockIdx.x * 256 + threadIdx.x;
  if (idx < 65536) {
    WqB[idx] = f2bf(in_proj_w[idx] * QSCALE);
  } else if (idx < 131072) {
    int i = idx - 65536;
    int m = i >> 7, c = i & 127;
    const float* wrow = in_proj_w + (size_t)(256 + m) * 256;
    float s = 0.f;
    for (int e2 = 0; e2 < 256; ++e2) s += wrow[e2] * kv_w[e2 * 128 + c];
    WkvB[i] = f2bf(s);
  } else if (idx < 196608) {
    int i = idx - 131072;
    int c = i >> 8, e2 = i & 255;
    float s = 0.f;
    for (int e = 0; e < 256; ++e)
      s += fuse_w[c * 256 + e] * out_proj_w[e * 256 + e2];
    M2B[i] = f2bf(s);
  } else if (idx < 196864) {
    int c = idx - 196608;
    float fbv = 0.f;
    for (int e = 0; e < 256; ++e) fbv += fuse_w[c * 256 + e] * out_proj_b[e];
    float inv = gamma[c] * rsqrtf(var[c] + 1e-5f);
    bnpk[c] = make_float2(inv, (fbv - mean[c]) * inv + beta[c]);
    qbias[c] = in_proj_b[c] * QSCALE;
  }
}

// ---------------------------------------------------------------------------
// Transpose-cast: tgt (B,256,1024) f32 -> tgtT (B,1024,256) bf16
//                 src (B,128,1024) f32 -> srcT (B,1024,128) bf16
// grid (16, 6, 8): by<4 -> tgt tiles, else src tiles. 64x64 tiles via LDS.
// ---------------------------------------------------------------------------
__global__ __launch_bounds__(256) void xpose(
    const float* __restrict__ tgt, const float* __restrict__ src,
    u16* __restrict__ tgtT, u16* __restrict__ srcT) {
  __shared__ u16 tile[64 * 65];
  int b = blockIdx.z, by = blockIdx.y, sb = blockIdx.x * 64;
  const float* X;
  u16* XT;
  int C, cb;
  if (by < 4) {
    X = tgt + (size_t)b * 256 * 1024;
    XT = tgtT + (size_t)b * 1024 * 256;
    C = 256;
    cb = by * 64;
  } else {
    X = src + (size_t)b * 128 * 1024;
    XT = srcT + (size_t)b * 1024 * 128;
    C = 128;
    cb = (by - 4) * 64;
  }
  int t = threadIdx.x;
  for (int i = t; i < 4096; i += 256) {
    int c = i >> 6, s = i & 63;
    tile[c * 65 + s] = f2bf(X[(size_t)(cb + c) * 1024 + sb + s]);
  }
  __syncthreads();
  for (int i = t; i < 4096; i += 256) {
    int s = i >> 6, c = i & 63;
    XT[(size_t)(sb + s) * C + cb + c] = tile[c * 65 + s];
  }
}

// ---------------------------------------------------------------------------
// QKV projection, LDS-free MFMA: frags loaded straight from global (L2-hot).
// grid (8, 12, 8): my<4 -> Q (WqB, K=256, tgtT); else KV (WkvB, K=128, srcT).
// Block = 4 waves; tile 64m x 128n; wave covers 64m x 32n (acc 4x2).
// ---------------------------------------------------------------------------
__global__ __launch_bounds__(256) void qkv_gemm(
    const u16* __restrict__ tgtT, const u16* __restrict__ srcT,
    const u16* __restrict__ WqB, const u16* __restrict__ WkvB,
    const float* __restrict__ qbias, const float* __restrict__ bkv,
    u16* __restrict__ QB, u16* __restrict__ KB, u16* __restrict__ VB) {
  int b = blockIdx.z, my = blockIdx.y, n0 = blockIdx.x * 128;
  bool isQ = my < 4;
  int m0 = isQ ? my * 64 : (my - 4) * 64;
  int Kd = isQ ? 256 : 128;
  const u16* Wp = isQ ? WqB : WkvB;
  const u16* Xp = isQ ? tgtT + (size_t)b * 1024 * 256
                      : srcT + (size_t)b * 1024 * 128;
  int t = threadIdx.x, wave = t >> 6, lane = t & 63;
  int lq = lane & 15, quad = lane >> 4;
  int nw = n0 + wave * 32;
  f32x4 acc[4][2];
#pragma unroll
  for (int mt = 0; mt < 4; ++mt)
#pragma unroll
    for (int nt = 0; nt < 2; ++nt) acc[mt][nt] = (f32x4){0.f, 0.f, 0.f, 0.f};

#pragma unroll 2
  for (int k0 = 0; k0 < Kd; k0 += 32) {
    short8 af[4], bf[2];
#pragma unroll
    for (int mt = 0; mt < 4; ++mt)
      af[mt] = *(const short8*)&Wp[(size_t)(m0 + mt * 16 + lq) * Kd + k0 + quad * 8];
#pragma unroll
    for (int nt = 0; nt < 2; ++nt)
      bf[nt] = *(const short8*)&Xp[(size_t)(nw + nt * 16 + lq) * Kd + k0 + quad * 8];
#pragma unroll
    for (int mt = 0; mt < 4; ++mt)
#pragma unroll
      for (int nt = 0; nt < 2; ++nt)
        acc[mt][nt] = __builtin_amdgcn_mfma_f32_16x16x32_bf16(af[mt], bf[nt],
                                                              acc[mt][nt], 0, 0, 0);
  }
  // D: row m = mt*16+quad*4+r, col n = nw + nt*16 + lq
  if (isQ) {
#pragma unroll
    for (int mt = 0; mt < 4; ++mt) {
      int e = m0 + mt * 16 + quad * 4;
      f32x4 bi = *(const f32x4*)&qbias[e];
#pragma unroll
      for (int nt = 0; nt < 2; ++nt) {
        int n = nw + nt * 16 + lq;
        u16x4 pk;
#pragma unroll
        for (int r = 0; r < 4; ++r) pk[r] = f2bf(acc[mt][nt][r] + bi[r]);
        *(u16x4*)&QB[((size_t)b * 1024 + n) * 256 + e] = pk;
      }
    }
  } else {
#pragma unroll
    for (int mt = 0; mt < 4; ++mt) {
      int m = m0 + mt * 16 + quad * 4;
      f32x4 bi = *(const f32x4*)&bkv[m];
#pragma unroll
      for (int nt = 0; nt < 2; ++nt) {
        int n = nw + nt * 16 + lq;
        if (m < 256) {
          int hh = m >> 5, d = m & 31;
          u16x4 pk;
#pragma unroll
          for (int r = 0; r < 4; ++r) pk[r] = f2bf(acc[mt][nt][r] + bi[r]);
          *(u16x4*)&KB[((size_t)(b * 8 + hh) * 1024 + n) * 32 + d] = pk;
        } else {
          int e = m - 256;
#pragma unroll
          for (int r = 0; r < 4; ++r)
            VB[((size_t)b * 256 + e + r) * 1024 + n] = f2bf(acc[mt][nt][r] + bi[r]);
        }
      }
    }
  }
}

// ---------------------------------------------------------------------------
// MFMA bf16 attention, 64-query blocks for occupancy. grid (16, 8, 8) = 1024.
// 4 waves x 16 q. LDS ~29KB -> 4 blocks/CU resident (grid-limited), 16 waves/CU.
// ---------------------------------------------------------------------------
__global__ __launch_bounds__(256) void attn_mfma(
    const u16* __restrict__ QB, const u16* __restrict__ KB,
    const u16* __restrict__ VB, u16* __restrict__ ctxB,
    float* __restrict__ attn_out) {
  __shared__ __align__(16) u16 Klds[128 * 40];    // [key][40]
  __shared__ __align__(16) u16 Vlds[32 * 136];    // [d][136]
  __shared__ __align__(16) u16 Plds[4][16 * 48];  // per-wave [q][48]
  __shared__ float colsum[1024];

  int b = blockIdx.z, h = blockIdx.y, q0 = blockIdx.x * 64;
  int t = threadIdx.x, wave = t >> 6, lane = t & 63;
  int lq = lane & 15, quad = lane >> 4;

  const u16* Qb = QB + (size_t)b * 1024 * 256 + h * 32;
  const u16* Kb = KB + (size_t)(b * 8 + h) * 1024 * 32;
  const u16* Vb = VB + (size_t)(b * 256 + h * 32) * 1024;

  short8 qf = *(const short8*)(Qb + (size_t)(q0 + wave * 16 + lq) * 256 + quad * 8);

  for (int i = t; i < 1024; i += 256) colsum[i] = 0.f;

  float lsum[4] = {0.f, 0.f, 0.f, 0.f};
  f32x4 O[2] = {(f32x4){0.f, 0.f, 0.f, 0.f}, (f32x4){0.f, 0.f, 0.f, 0.f}};
  const f32x4 zf = (f32x4){0.f, 0.f, 0.f, 0.f};
  u16* Pw = &Plds[wave][0];

  // ---------------- Pass A: exp, rowsum, O += P V ----------------
  for (int c0 = 0; c0 < 1024; c0 += 128) {
    __syncthreads();
    for (int i = t; i < 512; i += 256)
      *(short8*)&Klds[(i >> 2) * 40 + (i & 3) * 8] =
          *(const short8*)(Kb + (size_t)c0 * 32 + i * 8);
    for (int i = t; i < 512; i += 256) {
      int d = i >> 4, part = i & 15;
      *(short8*)&Vlds[d * 136 + part * 8] =
          *(const short8*)(Vb + (size_t)d * 1024 + c0 + part * 8);
    }
    __syncthreads();
#pragma unroll
    for (int pair = 0; pair < 4; ++pair) {
#pragma unroll
      for (int ntp = 0; ntp < 2; ++ntp) {
        int nt = pair * 2 + ntp;
        short8 kf = *(const short8*)&Klds[(nt * 16 + lq) * 40 + quad * 8];
        f32x4 s = __builtin_amdgcn_mfma_f32_16x16x32_bf16(qf, kf, zf, 0, 0, 0);
#pragma unroll
        for (int r = 0; r < 4; ++r) {
          float e = __expf(s[r]);
          lsum[r] += e;
          Pw[(quad * 4 + r) * 48 + ntp * 16 + lq] = f2bf_trunc(e);
        }
      }
      short8 pf = *(const short8*)&Pw[lq * 48 + quad * 8];
      short8 vf0 = *(const short8*)&Vlds[(0 * 16 + lq) * 136 + pair * 32 + quad * 8];
      short8 vf1 = *(const short8*)&Vlds[(1 * 16 + lq) * 136 + pair * 32 + quad * 8];
      O[0] = __builtin_amdgcn_mfma_f32_16x16x32_bf16(pf, vf0, O[0], 0, 0, 0);
      O[1] = __builtin_amdgcn_mfma_f32_16x16x32_bf16(pf, vf1, O[1], 0, 0, 0);
    }
  }

  // rowsum reduce over the 16 key-cols held across lq lanes -> 1/l per (quad,r)
  float linv[4];
#pragma unroll
  for (int r = 0; r < 4; ++r) {
    float v = lsum[r];
    v += __shfl_xor(v, 1);
    v += __shfl_xor(v, 2);
    v += __shfl_xor(v, 4);
    v += __shfl_xor(v, 8);
    linv[r] = 1.f / v;
  }

  // ctx bf16: row q = quad*4+r, col d = nt*16+lq
#pragma unroll
  for (int nt = 0; nt < 2; ++nt)
#pragma unroll
    for (int r = 0; r < 4; ++r) {
      int q = q0 + wave * 16 + quad * 4 + r;
      ctxB[((size_t)b * 1024 + q) * 256 + h * 32 + nt * 16 + lq] =
          f2bf(O[nt][r] * linv[r]);
    }

  // ---------------- Pass B: normalized column sums ----------------
  for (int c0 = 0; c0 < 1024; c0 += 128) {
    __syncthreads();
    for (int i = t; i < 512; i += 256)
      *(short8*)&Klds[(i >> 2) * 40 + (i & 3) * 8] =
          *(const short8*)(Kb + (size_t)c0 * 32 + i * 8);
    __syncthreads();
#pragma unroll
    for (int nt = 0; nt < 8; ++nt) {
      short8 kf = *(const short8*)&Klds[(nt * 16 + lq) * 40 + quad * 8];
      f32x4 s = __builtin_amdgcn_mfma_f32_16x16x32_bf16(qf, kf, zf, 0, 0, 0);
      float cs = 0.f;
#pragma unroll
      for (int r = 0; r < 4; ++r) cs += __expf(s[r]) * linv[r];
      cs += __shfl_xor(cs, 16);
      cs += __shfl_xor(cs, 32);
      if (quad == 0) atomicAdd(&colsum[c0 + nt * 16 + lq], cs);
    }
  }
  __syncthreads();
  for (int i = t; i < 1024; i += 256)
    atomicAdd(&attn_out[b * 1024 + i], colsum[i] * (1.f / 8192.f));
}

// ---------------------------------------------------------------------------
// Fused out GEMM + BN + SiLU + residual, LDS-free.
// grid (16, 4, 8); block 4 waves; tile 64c x 64s; wave covers 64c x 16s.
// ---------------------------------------------------------------------------
__global__ __launch_bounds__(256) void fused_out(
    const u16* __restrict__ M2B, const u16* __restrict__ ctxB,
    const float* __restrict__ tgt, const float2* __restrict__ bnpk,
    float* __restrict__ y) {
  int b = blockIdx.z, c0 = blockIdx.y * 64;
  int t = threadIdx.x, wave = t >> 6, lane = t & 63;
  int lq = lane & 15, quad = lane >> 4;
  int s0 = blockIdx.x * 64 + wave * 16;
  f32x4 acc[4];
#pragma unroll
  for (int mt = 0; mt < 4; ++mt) acc[mt] = (f32x4){0.f, 0.f, 0.f, 0.f};

#pragma unroll 4
  for (int k0 = 0; k0 < 256; k0 += 32) {
    short8 bf = *(const short8*)&ctxB[((size_t)b * 1024 + s0 + lq) * 256 + k0 + quad * 8];
    short8 af[4];
#pragma unroll
    for (int mt = 0; mt < 4; ++mt)
      af[mt] = *(const short8*)&M2B[(size_t)(c0 + mt * 16 + lq) * 256 + k0 + quad * 8];
#pragma unroll
    for (int mt = 0; mt < 4; ++mt)
      acc[mt] = __builtin_amdgcn_mfma_f32_16x16x32_bf16(af[mt], bf, acc[mt], 0, 0, 0);
  }
  int s = s0 + lq;
#pragma unroll
  for (int mt = 0; mt < 4; ++mt) {
#pragma unroll
    for (int r = 0; r < 4; ++r) {
      int c = c0 + mt * 16 + quad * 4 + r;
      float2 p = bnpk[c];
      float bn = acc[mt][r] * p.x + p.y;
      float sig = 1.f / (1.f + __expf(-bn));
      size_t idx = ((size_t)b * 256 + c) * 1024 + s;
      y[idx] = tgt[idx] + bn * sig;
    }
  }
}

// ---------------------------------------------------------------------------
extern "C" void kernel_launch(void* const* d_in, const int* in_sizes, int n_in,
                              void* d_out, int out_size, void* d_ws, size_t ws_size,
                              hipStream_t stream) {
  const float* tgt = (const float*)d_in[0];
  const float* src = (const float*)d_in[1];
  const float* kv_w = (const float*)d_in[2];
  const float* in_proj_w = (const float*)d_in[3];
  const float* in_proj_b = (const float*)d_in[4];
  const float* out_proj_w = (const float*)d_in[5];
  const float* out_proj_b = (const float*)d_in[6];
  const float* fuse_w = (const float*)d_in[7];
  const float* bn_gamma = (const float*)d_in[8];
  const float* bn_beta = (const float*)d_in[9];
  const float* bn_mean = (const float*)d_in[10];
  const float* bn_var = (const float*)d_in[11];

  char* W = (char*)d_ws;
  u16* WqB = (u16*)W;                    // 128KB
  u16* WkvB = (u16*)(W + 131072);        // 128KB
  u16* M2B = (u16*)(W + 262144);         // 128KB
  float* qbias = (float*)(W + 393216);   // 1KB
  float2* bnpk = (float2*)(W + 394240);  // 2KB
  u16* tgtT = (u16*)(W + 397312);        // 4MB (B,S,256)
  u16* srcT = tgtT + 2097152;            // 2MB (B,S,128)
  u16* QB = srcT + 1048576;              // 4MB (B,S,E)
  u16* KB = QB + 2097152;                // 4MB (B,nH,S,hd)
  u16* VB = KB + 2097152;                // 4MB (B,E,S)
  u16* ctxB = VB + 2097152;              // 4MB (B,S,E)

  float* y = (float*)d_out;
  float* attn_out = y + 2097152;

  hipMemsetAsync(attn_out, 0, 8192 * sizeof(float), stream);
  prep_kernel<<<769, 256, 0, stream>>>(in_proj_w, in_proj_b, kv_w, fuse_w,
                                       out_proj_w, out_proj_b, bn_gamma, bn_beta,
                                       bn_mean, bn_var, WqB, WkvB, M2B, qbias, bnpk);
  xpose<<<dim3(16, 6, 8), 256, 0, stream>>>(tgt, src, tgtT, srcT);
  qkv_gemm<<<dim3(8, 12, 8), 256, 0, stream>>>(tgtT, srcT, WqB, WkvB, qbias,
                                               in_proj_b + 256, QB, KB, VB);
  attn_mfma<<<dim3(16, 8, 8), 256, 0, stream>>>(QB, KB, VB, ctxB, attn_out);
  fused_out<<<dim3(16, 4, 8), 256, 0, stream>>>(M2B, ctxB, tgt, bnpk, y);
}